// Round 4
// baseline (6709913.281 us; speedup 1.0000x reference)
//
#include <hip/hip_runtime.h>

// EncoderPlanarLSTM: T=256,B=1024,DX=48,DA=16 (I=64), H=512, Z=32, F=4
// out = [mu(1024x32) | log_var(1024x32) | u(1024x128) | w(1024x128) | b(1024x4)] fp32

typedef __attribute__((__ext_vector_type__(8))) short bx8;   // 8 bf16 (4 VGPR)
typedef __attribute__((__ext_vector_type__(4))) float fx4;
typedef unsigned long long u64;

#define NSTEP 256
#define NKT   18          // K-tiles of 32 over K=576 (512 h + 64 y)
#define ROWB  1152        // bytes per A row in LDS (XOR-swizzled, no pad)
#define HBS   (1024 * 512)

__device__ __forceinline__ short bf16_of(float f) {
  union { float f; unsigned u; } c; c.f = f;
  unsigned r = c.u + 0x7fffu + ((c.u >> 16) & 1u);   // RNE
  return (short)(r >> 16);
}
__device__ __forceinline__ float fsigmoid(float x) {
  float e = __builtin_amdgcn_exp2f(-1.44269504f * x);
  return __builtin_amdgcn_rcpf(1.0f + e);
}
__device__ __forceinline__ float ftanh_(float x) {
  float e = __builtin_amdgcn_exp2f(2.88539008f * x);
  return 1.0f - 2.0f * __builtin_amdgcn_rcpf(1.0f + e);
}

// sc0 load: bypass L1, read current value from the XCD's shared L2.
#define H_LD(idx, off)                                                        \
  asm volatile("global_load_dwordx2 %0, %1, off offset:" #off " sc0"          \
               : "=v"(vb[idx]) : "v"(hq) : "memory")

// ---------------- pack masked+concat input to bf16, natural time order -------
__global__ __launch_bounds__(256) void pack_y_kernel(
    const float* __restrict__ x, const float* __restrict__ a,
    const float* __restrict__ mk, short* __restrict__ y) {
  const int idx = blockIdx.x * 256 + threadIdx.x;
  const float* xp = x + (size_t)idx * 48;
  const float* mp = mk + (size_t)idx * 48;
  const float* ap = a + (size_t)idx * 16;
  short* yp = y + (size_t)idx * 64;
  float v[64];
#pragma unroll
  for (int j = 0; j < 12; ++j) {
    fx4 xv = *(const fx4*)(xp + j * 4);
    fx4 mv = *(const fx4*)(mp + j * 4);
#pragma unroll
    for (int t = 0; t < 4; ++t) v[j * 4 + t] = xv[t] * mv[t];
  }
#pragma unroll
  for (int j = 0; j < 4; ++j) {
    fx4 av = *(const fx4*)(ap + j * 4);
#pragma unroll
    for (int t = 0; t < 4; ++t) v[48 + j * 4 + t] = av[t];
  }
#pragma unroll
  for (int c = 0; c < 8; ++c) {
    bx8 o;
#pragma unroll
    for (int t = 0; t < 8; ++t) o[t] = bf16_of(v[c * 8 + t]);
    *(bx8*)(yp + c * 8) = o;
  }
}

// ---------------- recurrent LSTM, weight-stationary, XCD-local exchange ------
// 256 WGs x 256 thr, 1 WG/CU (LDS-forced). Each WG claims a slot on ITS XCD:
// gb = xcc*2 + (k>>4), gn = k&15  ->  each 16-WG batch group is same-XCD by
// construction; h + flags exchange through that XCD's L2 (plain store / sc0 load).
// ctr: [512..519] per-XCD slot counters (MALL, once); [640..895] flag words.
__global__ __launch_bounds__(256, 1) void lstm_rec(
    const short* __restrict__ yw,      // [256][1024][64] bf16
    const float* __restrict__ w_hh,    // [2048][512]
    const float* __restrict__ w_ih,    // [2048][64]
    const float* __restrict__ b_ih, const float* __restrict__ b_hh,
    short* hbuf,                       // [2][1024][512] bf16
    float* __restrict__ hfinal,        // [1024][512]
    unsigned* ctr)
{
  __shared__ __align__(16) char Ash[82432];   // >81920 -> exactly 1 WG/CU
  __shared__ int s_gb, s_gn;
  const int tid = threadIdx.x;

  if (tid == 0) {
    unsigned xcc;
    asm volatile("s_getreg_b32 %0, hwreg(HW_REG_XCC_ID)" : "=s"(xcc));
    xcc &= 7u;
    unsigned k = __hip_atomic_fetch_add(ctr + 512 + xcc, 1u,
                                        __ATOMIC_RELAXED, __HIP_MEMORY_SCOPE_AGENT);
    s_gb = (int)(xcc * 2 + ((k >> 4) & 1));
    s_gn = (int)(k & 15);
  }
  __syncthreads();
  const int gb = s_gb;
  const int gn = s_gn;

  const int wv  = tid >> 6;
  const int lane = tid & 63;
  const int l15 = lane & 15;
  const int l4  = lane >> 4;
  const int bh  = wv >> 1;
  const int hh  = wv & 1;

  // ---- load resident B fragments (one-time) ----
  bx8 Bf[4 * NKT];
  float bias[4];
#pragma unroll
  for (int nt = 0; nt < 4; ++nt) {
    const int col = nt * 512 + gn * 32 + hh * 16 + l15;   // gate col in [0,2048)
    bias[nt] = b_ih[col] + b_hh[col];
#pragma unroll
    for (int kt = 0; kt < NKT; ++kt) {
      const int k0 = kt * 32 + l4 * 8;
      const float* src = (k0 < 512) ? (w_hh + (size_t)col * 512 + k0)
                                    : (w_ih + (size_t)col * 64 + (k0 - 512));
      fx4 w0 = *(const fx4*)(src);
      fx4 w1 = *(const fx4*)(src + 4);
      bx8 b;
#pragma unroll
      for (int t = 0; t < 4; ++t) { b[t] = bf16_of(w0[t]); b[4 + t] = bf16_of(w1[t]); }
      Bf[nt * NKT + kt] = b;
    }
  }

  float cst[8];
#pragma unroll
  for (int i = 0; i < 8; ++i) cst[i] = 0.f;

  // staging geometry: thread owns LDS row (tid>>2), 8B part (tid&3)
  const int srow = tid >> 2;
  const int part = tid & 3;
  const unsigned xsw = (unsigned)((srow & 7) << 4);
  const unsigned psw = (unsigned)(part * 8);
  char* lbase = Ash + srow * ROWB;
  const int growbase = gb * 64 + srow;

  // frag geometry
  const int row0  = bh * 32 + l15;
  const unsigned xm = (unsigned)((row0 & 7) << 4);
  const int aoff0 = row0 * ROWB;
  const int koff  = l4 * 16;
  const int colh  = gn * 32 + hh * 16 + l15;
  const bool evenl = (lane & 1) == 0;

  unsigned* fl = ctr + 640 + gb * 16;          // 16 flag words for this group
  unsigned* myfl = fl + gn;
  const unsigned* pollp = fl + (lane & 15);    // wave0 lanes poll all 16 (redundant >=16)

#pragma unroll 1
  for (int s = 0; s < NSTEP; ++s) {
    const short* hprev = hbuf + (size_t)(s & 1) * HBS;
    unsigned* hnext32 = (unsigned*)(hbuf + (size_t)((s + 1) & 1) * HBS);
    const short* ysl = yw + (size_t)(255 - s) * (1024 * 64);

    // ---- y loads: barrier-independent, issue early ----
    const u64* yq = (const u64*)(ysl + (size_t)growbase * 64) + part;
    u64 vy[4];
#pragma unroll
    for (int i = 0; i < 4; ++i) vy[i] = yq[i * 4];

    // ---- wait for h(s): poll the group's 16 single-writer flags via L2 ----
    if (s > 0) {
      if (tid < 64) {
        const unsigned tgt = (unsigned)s;
        unsigned guard = 0;
        for (;;) {
          unsigned v;
          asm volatile("global_load_dword %0, %1, off sc0\n\ts_waitcnt vmcnt(0)"
                       : "=v"(v) : "v"(pollp) : "memory");
          if (__all(v >= tgt)) break;
          if (++guard > (1u << 18)) break;     // bail: terminate, never hang
          __builtin_amdgcn_s_sleep(1);
        }
      }
      __syncthreads();
    }

    // ---- h loads: 32 x 8B sc0 (L2-local), one base + imm offsets ----
    const u64* hq = (const u64*)(hprev + (size_t)growbase * 512) + part;
    u64 vb[32];
    H_LD(0, 0);    H_LD(1, 32);   H_LD(2, 64);   H_LD(3, 96);
    H_LD(4, 128);  H_LD(5, 160);  H_LD(6, 192);  H_LD(7, 224);
    H_LD(8, 256);  H_LD(9, 288);  H_LD(10, 320); H_LD(11, 352);
    H_LD(12, 384); H_LD(13, 416); H_LD(14, 448); H_LD(15, 480);
    H_LD(16, 512); H_LD(17, 544); H_LD(18, 576); H_LD(19, 608);
    H_LD(20, 640); H_LD(21, 672); H_LD(22, 704); H_LD(23, 736);
    H_LD(24, 768); H_LD(25, 800); H_LD(26, 832); H_LD(27, 864);
    H_LD(28, 896); H_LD(29, 928); H_LD(30, 960); H_LD(31, 992);
    asm volatile("s_waitcnt vmcnt(0)" ::: "memory");

    // ---- LDS writes with XOR swizzle (matches read side; R1-proven) ----
#pragma unroll
    for (int i = 0; i < 32; ++i)
      *(u64*)(lbase + (int)((psw + i * 32) ^ xsw)) = vb[i];
#pragma unroll
    for (int i = 0; i < 4; ++i)
      *(u64*)(lbase + (int)((psw + 1024u + i * 32) ^ xsw)) = vy[i];
    __syncthreads();

    // ---- GEMM: acc[m][gate] += A(h|y) x W^T, B resident ----
    fx4 acc[8];
#pragma unroll
    for (int m = 0; m < 2; ++m)
#pragma unroll
      for (int nt = 0; nt < 4; ++nt) {
        fx4 z = {bias[nt], bias[nt], bias[nt], bias[nt]};
        acc[m * 4 + nt] = z;
      }
#pragma unroll
    for (int kt = 0; kt < NKT; ++kt) {
      const unsigned ko = (unsigned)(kt * 64 + koff);
      bx8 A0 = *(const bx8*)(Ash + aoff0 + (int)(ko ^ xm));
      bx8 A1 = *(const bx8*)(Ash + aoff0 + 16 * ROWB + (int)(ko ^ xm));
#pragma unroll
      for (int nt = 0; nt < 4; ++nt) {
        acc[nt]     = __builtin_amdgcn_mfma_f32_16x16x32_bf16(A0, Bf[nt * NKT + kt], acc[nt], 0, 0, 0);
        acc[4 + nt] = __builtin_amdgcn_mfma_f32_16x16x32_bf16(A1, Bf[nt * NKT + kt], acc[4 + nt], 0, 0, 0);
      }
    }

    // ---- gates, c/h update ----
    unsigned hb[8];
#pragma unroll
    for (int m = 0; m < 2; ++m) {
#pragma unroll
      for (int r = 0; r < 4; ++r) {
        float gi = acc[m * 4 + 0][r];
        float gf = acc[m * 4 + 1][r];
        float gg = acc[m * 4 + 2][r];
        float go = acc[m * 4 + 3][r];
        float c = fsigmoid(gf) * cst[m * 4 + r] + fsigmoid(gi) * ftanh_(gg);
        cst[m * 4 + r] = c;
        float h = fsigmoid(go) * ftanh_(c);
        hb[m * 4 + r] = (unsigned)(unsigned short)bf16_of(h);
        if (s == NSTEP - 1) {
          const int rowg = gb * 64 + bh * 32 + m * 16 + l4 * 4 + r;
          hfinal[(size_t)rowg * 512 + colh] = h;
        }
      }
    }

    if (s < NSTEP - 1) {
      // ---- publish h: pair-pack via shfl, 4 plain u32 stores to local L2 ----
#pragma unroll
      for (int r = 0; r < 4; ++r) {
        unsigned v0 = hb[r];                       // m=0
        unsigned v1 = hb[4 + r];                   // m=1
        unsigned p0 = (unsigned)__shfl_xor((int)v0, 1);
        unsigned p1 = (unsigned)__shfl_xor((int)v1, 1);
        unsigned packed = evenl ? (v0 | (p0 << 16)) : (p1 | (v1 << 16));
        const int m = evenl ? 0 : 1;
        const int rowg = gb * 64 + bh * 32 + m * 16 + l4 * 4 + r;
        hnext32[(size_t)rowg * 256 + (colh >> 1)] = packed;
      }
      asm volatile("s_waitcnt vmcnt(0)" ::: "memory");   // h(s+1) committed at L2
      __syncthreads();                                   // all 256 threads drained
      if (tid == 0) {
        unsigned sv = (unsigned)(s + 1);
        asm volatile("global_store_dword %0, %1, off" :: "v"(myfl), "v"(sv) : "memory");
      }
    }
  }
}

// ---------------- heads: exact fp32 VALU GEMM [1024 x 324 x 512] + epilogue --
__global__ __launch_bounds__(256) void heads_kernel(
    const float* __restrict__ hf,
    const float* __restrict__ lin_w, const float* __restrict__ lin_b,
    const float* __restrict__ lv_w,  const float* __restrict__ lv_b,
    const float* __restrict__ u_w,   const float* __restrict__ u_b,
    const float* __restrict__ ww_w,  const float* __restrict__ ww_b,
    const float* __restrict__ bf_w,  const float* __restrict__ bf_b,
    float* __restrict__ out)
{
  __shared__ float hs[64 * 513];
  const int tid = threadIdx.x;
  const int gb = blockIdx.x;     // 0..15
  const int cg = blockIdx.y;     // 0..5, 54 cols each
  for (int i = tid; i < 8192; i += 256) {
    fx4 v = *(const fx4*)(hf + (size_t)gb * 32768 + (size_t)i * 4);
    const int row = i >> 7;
    const int k = (i * 4) & 511;
    float* d = hs + row * 513 + k;
    d[0] = v[0]; d[1] = v[1]; d[2] = v[2]; d[3] = v[3];
  }
  __syncthreads();
  const int r = tid & 63;
  const int cq = tid >> 6;
  const float* hrow = hs + r * 513;
  const int b_ = gb * 64 + r;
#pragma unroll 1
  for (int j = 0; j < 14; ++j) {
    const int cl = cq + 4 * j;
    if (cl >= 54) break;
    const int C = cg * 54 + cl;      // 0..323
    const float* wp; float bv;
    if (C < 32)       { wp = lin_w + (size_t)C * 512;        bv = lin_b[C]; }
    else if (C < 64)  { wp = lv_w + (size_t)(C - 32) * 512;  bv = lv_b[C - 32]; }
    else if (C < 192) { wp = u_w + (size_t)(C - 64) * 512;   bv = u_b[C - 64]; }
    else if (C < 320) { wp = ww_w + (size_t)(C - 192) * 512; bv = ww_b[C - 192]; }
    else              { wp = bf_w + (size_t)(C - 320) * 512; bv = bf_b[C - 320]; }
    float dot = 0.f;
#pragma unroll 8
    for (int k = 0; k < 512; k += 4) {
      fx4 w = *(const fx4*)(wp + k);
      dot += hrow[k] * w[0] + hrow[k + 1] * w[1] + hrow[k + 2] * w[2] + hrow[k + 3] * w[3];
    }
    const float res = bv + dot;
    if (C < 32)       out[(size_t)b_ * 32 + C] = __builtin_amdgcn_exp2f(res * 1.44269504f) * 0.1f;
    else if (C < 64)  out[32768 + (size_t)b_ * 32 + (C - 32)] = res - 5.f;
    else if (C < 192) out[65536 + (size_t)b_ * 128 + (C - 64)] = res;
    else if (C < 320) out[196608 + (size_t)b_ * 128 + (C - 192)] = res;
    else              out[327680 + (size_t)b_ * 4 + (C - 320)] = res;
  }
}

extern "C" void kernel_launch(void* const* d_in, const int* in_sizes, int n_in,
                              void* d_out, int out_size, void* d_ws, size_t ws_size,
                              hipStream_t stream) {
  (void)in_sizes; (void)n_in; (void)out_size; (void)ws_size;
  const float* x     = (const float*)d_in[0];
  const float* a     = (const float*)d_in[1];
  const float* mask  = (const float*)d_in[2];
  const float* w_ih  = (const float*)d_in[3];
  const float* w_hh  = (const float*)d_in[4];
  const float* b_ih  = (const float*)d_in[5];
  const float* b_hh  = (const float*)d_in[6];
  const float* lin_w = (const float*)d_in[7];
  const float* lin_b = (const float*)d_in[8];
  const float* lv_w  = (const float*)d_in[9];
  const float* lv_b  = (const float*)d_in[10];
  const float* u_w   = (const float*)d_in[11];
  const float* u_b   = (const float*)d_in[12];
  const float* ww_w  = (const float*)d_in[13];
  const float* ww_b  = (const float*)d_in[14];
  const float* bf_w  = (const float*)d_in[15];
  const float* bf_b  = (const float*)d_in[16];

  char* ws = (char*)d_ws;
  short* yw       = (short*)(ws);                 // 33,554,432 B: [256][1024][64] bf16
  short* hbuf     = (short*)(ws + 33554432);      //  2,097,152 B: [2][1024][512] bf16
  float* hfinal   = (float*)(ws + 35651584);      //  2,097,152 B
  unsigned* ctr   = (unsigned*)(ws + 37748736);   //      4,096 B

  hipMemsetAsync(hbuf, 0, 1024 * 512 * 2, stream);   // h(0) = 0
  hipMemsetAsync(ctr, 0, 4096, stream);

  pack_y_kernel<<<1024, 256, 0, stream>>>(x, a, mask, yw);
  lstm_rec<<<256, 256, 0, stream>>>(yw, w_hh, w_ih, b_ih, b_hh, hbuf, hfinal, ctr);
  heads_kernel<<<dim3(16, 6), 256, 0, stream>>>(hfinal, lin_w, lin_b, lv_w, lv_b,
                                                u_w, u_b, ww_w, ww_b, bf_w, bf_b,
                                                (float*)d_out);
}

// Round 5
// 1818.823 us; speedup vs baseline: 3689.1523x; 3689.1523x over previous
//
#include <hip/hip_runtime.h>

// EncoderPlanarLSTM: T=256,B=1024,DX=48,DA=16 (I=64), H=512, Z=32, F=4
// out = [mu(1024x32) | log_var(1024x32) | u(1024x128) | w(1024x128) | b(1024x4)] fp32

typedef __attribute__((__ext_vector_type__(8))) short bx8;   // 8 bf16 (4 VGPR)
typedef __attribute__((__ext_vector_type__(4))) float fx4;
typedef unsigned long long u64;

#define NSTEP 256
#define NKT   18          // K-tiles of 32 over K=576 (512 h + 64 y)
#define ROWB  1184        // LDS bytes per A row: 1152 data + 32 pad (rotates bank phase)
#define HBS   (1024 * 512)

__device__ __forceinline__ short bf16_of(float f) {
  union { float f; unsigned u; } c; c.f = f;
  unsigned r = c.u + 0x7fffu + ((c.u >> 16) & 1u);   // RNE
  return (short)(r >> 16);
}
__device__ __forceinline__ float fsigmoid(float x) {
  float e = __builtin_amdgcn_exp2f(-1.44269504f * x);
  return __builtin_amdgcn_rcpf(1.0f + e);
}
__device__ __forceinline__ float ftanh_(float x) {
  float e = __builtin_amdgcn_exp2f(2.88539008f * x);
  return 1.0f - 2.0f * __builtin_amdgcn_rcpf(1.0f + e);
}

// ---------------- pack masked+concat input to bf16, natural time order -------
__global__ __launch_bounds__(256) void pack_y_kernel(
    const float* __restrict__ x, const float* __restrict__ a,
    const float* __restrict__ mk, short* __restrict__ y) {
  const int idx = blockIdx.x * 256 + threadIdx.x;
  const float* xp = x + (size_t)idx * 48;
  const float* mp = mk + (size_t)idx * 48;
  const float* ap = a + (size_t)idx * 16;
  short* yp = y + (size_t)idx * 64;
  float v[64];
#pragma unroll
  for (int j = 0; j < 12; ++j) {
    fx4 xv = *(const fx4*)(xp + j * 4);
    fx4 mv = *(const fx4*)(mp + j * 4);
#pragma unroll
    for (int t = 0; t < 4; ++t) v[j * 4 + t] = xv[t] * mv[t];
  }
#pragma unroll
  for (int j = 0; j < 4; ++j) {
    fx4 av = *(const fx4*)(ap + j * 4);
#pragma unroll
    for (int t = 0; t < 4; ++t) v[48 + j * 4 + t] = av[t];
  }
#pragma unroll
  for (int c = 0; c < 8; ++c) {
    bx8 o;
#pragma unroll
    for (int t = 0; t < 8; ++t) o[t] = bf16_of(v[c * 8 + t]);
    *(bx8*)(yp + c * 8) = o;
  }
}

// ---------------- recurrent LSTM, weight-stationary, MALL exchange (R2-proven)
// grid 256 WGs x 256 thr, 1 WG/CU (LDS-forced). WG(gb=wg&15, gn=wg>>4):
// batch rows gb*64..+64, h-cols gn*32..+32. h + flags via AGENT-scope atomics.
// Split-phase step: poll -> issue h loads -> stage+MFMA y -> stage h -> MFMA h.
__global__ __launch_bounds__(256, 1) void lstm_rec(
    const short* __restrict__ yw,      // [256][1024][64] bf16
    const float* __restrict__ w_hh,    // [2048][512]
    const float* __restrict__ w_ih,    // [2048][64]
    const float* __restrict__ b_ih, const float* __restrict__ b_hh,
    short* hbuf,                       // [2][1024][512] bf16
    float* __restrict__ hfinal,        // [1024][512]
    unsigned* ctr)                     // flags at [1024 + (gb*16+gn)*16]
{
  __shared__ __align__(16) char Ash[82432];   // >81920 -> exactly 1 WG/CU
  const int tid = threadIdx.x;
  const int wg  = blockIdx.x;
  const int gb  = wg & 15;
  const int gn  = wg >> 4;
  const int wv  = tid >> 6;
  const int lane = tid & 63;
  const int l15 = lane & 15;
  const int l4  = lane >> 4;
  const int bh  = wv >> 1;
  const int hh  = wv & 1;

  // ---- load resident B fragments (one-time) ----
  bx8 Bf[4 * NKT];
  float bias[4];
#pragma unroll
  for (int nt = 0; nt < 4; ++nt) {
    const int col = nt * 512 + gn * 32 + hh * 16 + l15;   // gate col in [0,2048)
    bias[nt] = b_ih[col] + b_hh[col];
#pragma unroll
    for (int kt = 0; kt < NKT; ++kt) {
      const int k0 = kt * 32 + l4 * 8;
      const float* src = (k0 < 512) ? (w_hh + (size_t)col * 512 + k0)
                                    : (w_ih + (size_t)col * 64 + (k0 - 512));
      fx4 w0 = *(const fx4*)(src);
      fx4 w1 = *(const fx4*)(src + 4);
      bx8 b;
#pragma unroll
      for (int t = 0; t < 4; ++t) { b[t] = bf16_of(w0[t]); b[4 + t] = bf16_of(w1[t]); }
      Bf[nt * NKT + kt] = b;
    }
  }

  float cst[8];
#pragma unroll
  for (int i = 0; i < 8; ++i) cst[i] = 0.f;

  // staging geometry: thread owns LDS row (tid>>2), 8B part (tid&3)
  const int srow = tid >> 2;
  const int part = tid & 3;
  const unsigned xsw = (unsigned)((srow & 7) << 4);
  const unsigned psw = (unsigned)(part * 8);
  char* lbase = Ash + srow * ROWB;
  const int growbase = gb * 64 + srow;

  // frag geometry
  const int row0  = bh * 32 + l15;
  const unsigned xm = (unsigned)((row0 & 7) << 4);
  const int aoff0 = row0 * ROWB;
  const int koff  = l4 * 16;
  const int colh  = gn * 32 + hh * 16 + l15;
  const bool evenl = (lane & 1) == 0;

  unsigned* fl = ctr + 1024 + gb * 256;             // 16 flags, 64B apart
  unsigned* myfl = fl + gn * 16;
  const unsigned* pollp = fl + (lane & 15) * 16;

#pragma unroll 1
  for (int s = 0; s < NSTEP; ++s) {
    const short* hprev = hbuf + (size_t)(s & 1) * HBS;
    unsigned* hnext32 = (unsigned*)(hbuf + (size_t)((s + 1) & 1) * HBS);
    const short* ysl = yw + (size_t)(255 - s) * (1024 * 64);

    // ---- y loads: barrier-independent, issue before the poll ----
    const u64* yq = (const u64*)(ysl + (size_t)growbase * 64) + part;
    u64 vy[4];
#pragma unroll
    for (int i = 0; i < 4; ++i) vy[i] = yq[i * 4];

    // ---- wait for h(s): poll 16 single-writer flags (agent atomics) ----
    if (s > 0) {
      if (tid < 64) {
        const unsigned tgt = (unsigned)s;
        unsigned guard = 0;
        for (;;) {
          unsigned v = __hip_atomic_load(pollp, __ATOMIC_RELAXED, __HIP_MEMORY_SCOPE_AGENT);
          if (__all(v >= tgt)) break;
          if (++guard > (1u << 18)) break;     // bail: terminate, never hang
          __builtin_amdgcn_s_sleep(1);
        }
      }
      // raw barrier: release other waves WITHOUT draining their y loads
      __builtin_amdgcn_s_barrier();
    }

    // ---- issue all 32 h loads (8B agent-atomic, R2-proven visibility) ----
    const u64* hq = (const u64*)(hprev + (size_t)growbase * 512) + part;
    u64 vb[32];
#pragma unroll
    for (int i = 0; i < 32; ++i)
      vb[i] = __hip_atomic_load(hq + i * 4, __ATOMIC_RELAXED, __HIP_MEMORY_SCOPE_AGENT);

    // ---- stage y tiles (kt 16,17) and MFMA them while h is in flight ----
#pragma unroll
    for (int i = 0; i < 4; ++i)
      *(u64*)(lbase + (int)((psw + 1024u + i * 32) ^ xsw)) = vy[i];
    asm volatile("s_waitcnt lgkmcnt(0)" ::: "memory");
    __builtin_amdgcn_sched_barrier(0);
    __builtin_amdgcn_s_barrier();

    fx4 acc[8];
#pragma unroll
    for (int m = 0; m < 2; ++m)
#pragma unroll
      for (int nt = 0; nt < 4; ++nt) {
        fx4 z = {bias[nt], bias[nt], bias[nt], bias[nt]};
        acc[m * 4 + nt] = z;
      }
#pragma unroll
    for (int kt = 16; kt < 18; ++kt) {
      const unsigned ko = (unsigned)(kt * 64 + koff);
      bx8 A0 = *(const bx8*)(Ash + aoff0 + (int)(ko ^ xm));
      bx8 A1 = *(const bx8*)(Ash + aoff0 + 16 * ROWB + (int)(ko ^ xm));
#pragma unroll
      for (int nt = 0; nt < 4; ++nt) {
        acc[nt]     = __builtin_amdgcn_mfma_f32_16x16x32_bf16(A0, Bf[nt * NKT + kt], acc[nt], 0, 0, 0);
        acc[4 + nt] = __builtin_amdgcn_mfma_f32_16x16x32_bf16(A1, Bf[nt * NKT + kt], acc[4 + nt], 0, 0, 0);
      }
    }

    // ---- stage h tiles (compiler inserts the vmcnt wait on vb here) ----
#pragma unroll
    for (int i = 0; i < 32; ++i)
      *(u64*)(lbase + (int)((psw + i * 32) ^ xsw)) = vb[i];
    asm volatile("s_waitcnt lgkmcnt(0)" ::: "memory");
    __builtin_amdgcn_sched_barrier(0);
    __builtin_amdgcn_s_barrier();

    // ---- MFMA h tiles (kt 0..15) ----
#pragma unroll
    for (int kt = 0; kt < 16; ++kt) {
      const unsigned ko = (unsigned)(kt * 64 + koff);
      bx8 A0 = *(const bx8*)(Ash + aoff0 + (int)(ko ^ xm));
      bx8 A1 = *(const bx8*)(Ash + aoff0 + 16 * ROWB + (int)(ko ^ xm));
#pragma unroll
      for (int nt = 0; nt < 4; ++nt) {
        acc[nt]     = __builtin_amdgcn_mfma_f32_16x16x32_bf16(A0, Bf[nt * NKT + kt], acc[nt], 0, 0, 0);
        acc[4 + nt] = __builtin_amdgcn_mfma_f32_16x16x32_bf16(A1, Bf[nt * NKT + kt], acc[4 + nt], 0, 0, 0);
      }
    }

    // ---- gates, c/h update ----
    unsigned hb[8];
#pragma unroll
    for (int m = 0; m < 2; ++m) {
#pragma unroll
      for (int r = 0; r < 4; ++r) {
        float gi = acc[m * 4 + 0][r];
        float gf = acc[m * 4 + 1][r];
        float gg = acc[m * 4 + 2][r];
        float go = acc[m * 4 + 3][r];
        float c = fsigmoid(gf) * cst[m * 4 + r] + fsigmoid(gi) * ftanh_(gg);
        cst[m * 4 + r] = c;
        float h = fsigmoid(go) * ftanh_(c);
        hb[m * 4 + r] = (unsigned)(unsigned short)bf16_of(h);
        if (s == NSTEP - 1) {
          const int rowg = gb * 64 + bh * 32 + m * 16 + l4 * 4 + r;
          hfinal[(size_t)rowg * 512 + colh] = h;
        }
      }
    }

    if (s < NSTEP - 1) {
      // ---- publish h: pair-pack via shfl, 4 agent-atomic u32 stores ----
#pragma unroll
      for (int r = 0; r < 4; ++r) {
        unsigned v0 = hb[r];                       // m=0
        unsigned v1 = hb[4 + r];                   // m=1
        unsigned p0 = (unsigned)__shfl_xor((int)v0, 1);
        unsigned p1 = (unsigned)__shfl_xor((int)v1, 1);
        unsigned packed = evenl ? (v0 | (p0 << 16)) : (p1 | (v1 << 16));
        const int m = evenl ? 0 : 1;
        const int rowg = gb * 64 + bh * 32 + m * 16 + l4 * 4 + r;
        __hip_atomic_store(hnext32 + (size_t)rowg * 256 + (colh >> 1), packed,
                           __ATOMIC_RELAXED, __HIP_MEMORY_SCOPE_AGENT);
      }
      asm volatile("s_waitcnt vmcnt(0)" ::: "memory");   // h(s+1) at coherence point
      __syncthreads();                                   // all 256 threads drained
      if (tid == 0)
        __hip_atomic_store(myfl, (unsigned)(s + 1),
                           __ATOMIC_RELAXED, __HIP_MEMORY_SCOPE_AGENT);
    }
  }
}

// ---------------- heads: exact fp32 VALU GEMM [1024 x 324 x 512] + epilogue --
__global__ __launch_bounds__(256) void heads_kernel(
    const float* __restrict__ hf,
    const float* __restrict__ lin_w, const float* __restrict__ lin_b,
    const float* __restrict__ lv_w,  const float* __restrict__ lv_b,
    const float* __restrict__ u_w,   const float* __restrict__ u_b,
    const float* __restrict__ ww_w,  const float* __restrict__ ww_b,
    const float* __restrict__ bf_w,  const float* __restrict__ bf_b,
    float* __restrict__ out)
{
  __shared__ float hs[64 * 513];
  const int tid = threadIdx.x;
  const int gb = blockIdx.x;     // 0..15
  const int cg = blockIdx.y;     // 0..5, 54 cols each
  for (int i = tid; i < 8192; i += 256) {
    fx4 v = *(const fx4*)(hf + (size_t)gb * 32768 + (size_t)i * 4);
    const int row = i >> 7;
    const int k = (i * 4) & 511;
    float* d = hs + row * 513 + k;
    d[0] = v[0]; d[1] = v[1]; d[2] = v[2]; d[3] = v[3];
  }
  __syncthreads();
  const int r = tid & 63;
  const int cq = tid >> 6;
  const float* hrow = hs + r * 513;
  const int b_ = gb * 64 + r;
#pragma unroll 1
  for (int j = 0; j < 14; ++j) {
    const int cl = cq + 4 * j;
    if (cl >= 54) break;
    const int C = cg * 54 + cl;      // 0..323
    const float* wp; float bv;
    if (C < 32)       { wp = lin_w + (size_t)C * 512;        bv = lin_b[C]; }
    else if (C < 64)  { wp = lv_w + (size_t)(C - 32) * 512;  bv = lv_b[C - 32]; }
    else if (C < 192) { wp = u_w + (size_t)(C - 64) * 512;   bv = u_b[C - 64]; }
    else if (C < 320) { wp = ww_w + (size_t)(C - 192) * 512; bv = ww_b[C - 192]; }
    else              { wp = bf_w + (size_t)(C - 320) * 512; bv = bf_b[C - 320]; }
    float dot = 0.f;
#pragma unroll 8
    for (int k = 0; k < 512; k += 4) {
      fx4 w = *(const fx4*)(wp + k);
      dot += hrow[k] * w[0] + hrow[k + 1] * w[1] + hrow[k + 2] * w[2] + hrow[k + 3] * w[3];
    }
    const float res = bv + dot;
    if (C < 32)       out[(size_t)b_ * 32 + C] = __builtin_amdgcn_exp2f(res * 1.44269504f) * 0.1f;
    else if (C < 64)  out[32768 + (size_t)b_ * 32 + (C - 32)] = res - 5.f;
    else if (C < 192) out[65536 + (size_t)b_ * 128 + (C - 64)] = res;
    else if (C < 320) out[196608 + (size_t)b_ * 128 + (C - 192)] = res;
    else              out[327680 + (size_t)b_ * 4 + (C - 320)] = res;
  }
}

extern "C" void kernel_launch(void* const* d_in, const int* in_sizes, int n_in,
                              void* d_out, int out_size, void* d_ws, size_t ws_size,
                              hipStream_t stream) {
  (void)in_sizes; (void)n_in; (void)out_size; (void)ws_size;
  const float* x     = (const float*)d_in[0];
  const float* a     = (const float*)d_in[1];
  const float* mask  = (const float*)d_in[2];
  const float* w_ih  = (const float*)d_in[3];
  const float* w_hh  = (const float*)d_in[4];
  const float* b_ih  = (const float*)d_in[5];
  const float* b_hh  = (const float*)d_in[6];
  const float* lin_w = (const float*)d_in[7];
  const float* lin_b = (const float*)d_in[8];
  const float* lv_w  = (const float*)d_in[9];
  const float* lv_b  = (const float*)d_in[10];
  const float* u_w   = (const float*)d_in[11];
  const float* u_b   = (const float*)d_in[12];
  const float* ww_w  = (const float*)d_in[13];
  const float* ww_b  = (const float*)d_in[14];
  const float* bf_w  = (const float*)d_in[15];
  const float* bf_b  = (const float*)d_in[16];

  char* ws = (char*)d_ws;
  short* yw       = (short*)(ws);                 // 33,554,432 B: [256][1024][64] bf16
  short* hbuf     = (short*)(ws + 33554432);      //  2,097,152 B: [2][1024][512] bf16
  float* hfinal   = (float*)(ws + 35651584);      //  2,097,152 B
  unsigned* ctr   = (unsigned*)(ws + 37748736);   //     24,576 B (flags region)

  hipMemsetAsync(hbuf, 0, 1024 * 512 * 2, stream);   // h(0) = 0
  hipMemsetAsync(ctr, 0, 24576, stream);

  pack_y_kernel<<<1024, 256, 0, stream>>>(x, a, mask, yw);
  lstm_rec<<<256, 256, 0, stream>>>(yw, w_hh, w_ih, b_ih, b_hh, hbuf, hfinal, ctr);
  heads_kernel<<<dim3(16, 6), 256, 0, stream>>>(hfinal, lin_w, lin_b, lv_w, lv_b,
                                                u_w, u_b, ww_w, ww_b, bf_w, bf_b,
                                                (float*)d_out);
}

// Round 6
// 1473.419 us; speedup vs baseline: 4553.9758x; 1.2344x over previous
//
#include <hip/hip_runtime.h>

// EncoderPlanarLSTM: T=256,B=1024,DX=48,DA=16 (I=64), H=512, Z=32, F=4
// out = [mu(1024x32) | log_var(1024x32) | u(1024x128) | w(1024x128) | b(1024x4)] fp32

typedef __attribute__((__ext_vector_type__(8))) short bx8;   // 8 bf16 (4 VGPR)
typedef __attribute__((__ext_vector_type__(4))) float fx4;
typedef __attribute__((__ext_vector_type__(4))) unsigned ux4;
typedef unsigned long long u64;

#define NSTEP 256
#define NKT   18          // K-tiles of 32 over K=576 (512 h + 64 y)
#define ROWB  1184        // LDS bytes per A row (1152 data + 32 pad)
#define TRPOFF 75776      // transpose staging region (64*1184 = 75776)
#define HBS   (1024 * 512)

__device__ __forceinline__ short bf16_of(float f) {
  union { float f; unsigned u; } c; c.f = f;
  unsigned r = c.u + 0x7fffu + ((c.u >> 16) & 1u);   // RNE
  return (short)(r >> 16);
}
__device__ __forceinline__ float fsigmoid(float x) {
  float e = __builtin_amdgcn_exp2f(-1.44269504f * x);
  return __builtin_amdgcn_rcpf(1.0f + e);
}
__device__ __forceinline__ float ftanh_(float x) {
  float e = __builtin_amdgcn_exp2f(2.88539008f * x);
  return 1.0f - 2.0f * __builtin_amdgcn_rcpf(1.0f + e);
}

// MALL-coherent 16B load/store (same sc0 sc1 bits the R2-proven agent atomics
// emit, but raw instructions -> fully pipelined, one vmcnt(0) for the batch).
#define H_LD4(idx, off)                                                       \
  asm volatile("global_load_dwordx4 %0, %1, off offset:" #off " sc0 sc1"      \
               : "=v"(vh[idx]) : "v"(hq) : "memory")

// ---------------- pack masked+concat input to bf16, natural time order -------
__global__ __launch_bounds__(256) void pack_y_kernel(
    const float* __restrict__ x, const float* __restrict__ a,
    const float* __restrict__ mk, short* __restrict__ y) {
  const int idx = blockIdx.x * 256 + threadIdx.x;
  const float* xp = x + (size_t)idx * 48;
  const float* mp = mk + (size_t)idx * 48;
  const float* ap = a + (size_t)idx * 16;
  short* yp = y + (size_t)idx * 64;
  float v[64];
#pragma unroll
  for (int j = 0; j < 12; ++j) {
    fx4 xv = *(const fx4*)(xp + j * 4);
    fx4 mv = *(const fx4*)(mp + j * 4);
#pragma unroll
    for (int t = 0; t < 4; ++t) v[j * 4 + t] = xv[t] * mv[t];
  }
#pragma unroll
  for (int j = 0; j < 4; ++j) {
    fx4 av = *(const fx4*)(ap + j * 4);
#pragma unroll
    for (int t = 0; t < 4; ++t) v[48 + j * 4 + t] = av[t];
  }
#pragma unroll
  for (int c = 0; c < 8; ++c) {
    bx8 o;
#pragma unroll
    for (int t = 0; t < 8; ++t) o[t] = bf16_of(v[c * 8 + t]);
    *(bx8*)(yp + c * 8) = o;
  }
}

// ---------------- recurrent LSTM, weight-stationary, pipelined MALL exchange --
// grid 256 WGs x 256 thr, 1 WG/CU (LDS-forced). WG(gb=wg&15, gn=wg>>4):
// batch rows gb*64..+64, h-cols gn*32..+32.
__global__ __launch_bounds__(256, 1) void lstm_rec(
    const short* __restrict__ yw,      // [256][1024][64] bf16
    const float* __restrict__ w_hh,    // [2048][512]
    const float* __restrict__ w_ih,    // [2048][64]
    const float* __restrict__ b_ih, const float* __restrict__ b_hh,
    short* hbuf,                       // [2][1024][512] bf16
    float* __restrict__ hfinal,        // [1024][512]
    unsigned* ctr)                     // flags at [1024 + (gb*16+gn)*16]
{
  __shared__ __align__(16) char Ash[82432];   // >81920 -> exactly 1 WG/CU
  const int tid = threadIdx.x;
  const int wg  = blockIdx.x;
  const int gb  = wg & 15;
  const int gn  = wg >> 4;
  const int wv  = tid >> 6;
  const int lane = tid & 63;
  const int l15 = lane & 15;
  const int l4  = lane >> 4;
  const int bh  = wv >> 1;
  const int hh  = wv & 1;

  // ---- load resident B fragments (one-time; live in unified VGPR/AGPR) ----
  bx8 Bf[4 * NKT];
  float bias[4];
#pragma unroll
  for (int nt = 0; nt < 4; ++nt) {
    const int col = nt * 512 + gn * 32 + hh * 16 + l15;   // gate col in [0,2048)
    bias[nt] = b_ih[col] + b_hh[col];
#pragma unroll
    for (int kt = 0; kt < NKT; ++kt) {
      const int k0 = kt * 32 + l4 * 8;
      const float* src = (k0 < 512) ? (w_hh + (size_t)col * 512 + k0)
                                    : (w_ih + (size_t)col * 64 + (k0 - 512));
      fx4 w0 = *(const fx4*)(src);
      fx4 w1 = *(const fx4*)(src + 4);
      bx8 b;
#pragma unroll
      for (int t = 0; t < 4; ++t) { b[t] = bf16_of(w0[t]); b[4 + t] = bf16_of(w1[t]); }
      Bf[nt * NKT + kt] = b;
    }
  }

  float cst[8];
#pragma unroll
  for (int i = 0; i < 8; ++i) cst[i] = 0.f;

  // staging geometry: thread owns LDS row (tid>>2), 16B part (tid&3)
  const int srow = tid >> 2;
  const int part = tid & 3;
  const unsigned xsw = (unsigned)((srow & 7) << 4);
  char* lbase = Ash + srow * ROWB;
  const int growbase = gb * 64 + srow;

  // frag geometry
  const int row0  = bh * 32 + l15;
  const unsigned xm = (unsigned)((row0 & 7) << 4);
  const int aoff0 = row0 * ROWB;
  const int koff  = l4 * 16;
  const int colh  = gn * 32 + hh * 16 + l15;
  const bool evenl = (lane & 1) == 0;

  // publish-transpose geometry
  char* trp = Ash + TRPOFF;                       // [64 rows][16 u32]
  const int pidx = hh * 8 + (l15 >> 1);
  const int mloc = evenl ? 0 : 1;
  const int rbase = bh * 32 + mloc * 16 + l4 * 4;
  const int prow = tid >> 2;                      // coalesced-store row
  const int pc   = tid & 3;                       // 16B chunk in 64B row slab

  unsigned* fl = ctr + 1024 + gb * 256;           // 16 flags, 64B apart
  unsigned* myfl = fl + gn * 16;
  const unsigned* pollp = fl + (lane & 15) * 16;

#pragma unroll 1
  for (int s = 0; s < NSTEP; ++s) {
    const char* hprevb = (const char*)(hbuf + (size_t)(s & 1) * HBS);
    char* hnextb = (char*)(hbuf + (size_t)((s + 1) & 1) * HBS);
    const short* ysl = yw + (size_t)(255 - s) * (1024 * 64);

    // ---- y loads: flag-independent, issue before the poll ----
    const char* yrow = (const char*)(ysl + (size_t)growbase * 64);
    ux4 vy[2];
#pragma unroll
    for (int j = 0; j < 2; ++j)
      vy[j] = *(const ux4*)(yrow + part * 32 + j * 16);

    // ---- wait for h(s): poll 16 single-writer flags at the MALL ----
    if (s > 0) {
      if (tid < 64) {
        const unsigned tgt = (unsigned)s;
        unsigned guard = 0;
        for (;;) {
          unsigned v;
          asm volatile("global_load_dword %0, %1, off sc0 sc1\n\ts_waitcnt vmcnt(0)"
                       : "=v"(v) : "v"(pollp) : "memory");
          if (__all(v >= tgt)) break;
          if (++guard > (1u << 18)) break;       // bail: terminate, never hang
          __builtin_amdgcn_s_sleep(1);
        }
      }
      __builtin_amdgcn_s_barrier();              // release all waves; gate staging
    }

    // ---- h loads: 16 x 16B sc0 sc1, all in flight, one vmcnt ----
    const char* hq = hprevb + (size_t)growbase * 1024 + part * 16;
    ux4 vh[16];
    H_LD4(0, 0);    H_LD4(1, 64);   H_LD4(2, 128);  H_LD4(3, 192);
    H_LD4(4, 256);  H_LD4(5, 320);  H_LD4(6, 384);  H_LD4(7, 448);
    H_LD4(8, 512);  H_LD4(9, 576);  H_LD4(10, 640); H_LD4(11, 704);
    H_LD4(12, 768); H_LD4(13, 832); H_LD4(14, 896); H_LD4(15, 960);
    asm volatile("s_waitcnt vmcnt(0)" ::: "memory");

    // ---- LDS staging with 16B-granule XOR swizzle (matches read side) ----
#pragma unroll
    for (int i = 0; i < 16; ++i)
      *(ux4*)(lbase + (int)(((unsigned)(part * 16 + i * 64)) ^ xsw)) = vh[i];
#pragma unroll
    for (int j = 0; j < 2; ++j)
      *(ux4*)(lbase + (int)((1024u + part * 32 + j * 16) ^ xsw)) = vy[j];
    asm volatile("s_waitcnt lgkmcnt(0)" ::: "memory");
    __builtin_amdgcn_sched_barrier(0);
    __builtin_amdgcn_s_barrier();

    // ---- GEMM: acc[m][gate] += A(h|y) x W^T, B resident ----
    fx4 acc[8];
#pragma unroll
    for (int m = 0; m < 2; ++m)
#pragma unroll
      for (int nt = 0; nt < 4; ++nt) {
        fx4 z = {bias[nt], bias[nt], bias[nt], bias[nt]};
        acc[m * 4 + nt] = z;
      }
#pragma unroll
    for (int kt = 0; kt < NKT; ++kt) {
      const unsigned ko = (unsigned)(kt * 64 + koff);
      bx8 A0 = *(const bx8*)(Ash + aoff0 + (int)(ko ^ xm));
      bx8 A1 = *(const bx8*)(Ash + aoff0 + 16 * ROWB + (int)(ko ^ xm));
#pragma unroll
      for (int nt = 0; nt < 4; ++nt) {
        acc[nt]     = __builtin_amdgcn_mfma_f32_16x16x32_bf16(A0, Bf[nt * NKT + kt], acc[nt], 0, 0, 0);
        acc[4 + nt] = __builtin_amdgcn_mfma_f32_16x16x32_bf16(A1, Bf[nt * NKT + kt], acc[4 + nt], 0, 0, 0);
      }
    }

    // ---- gates, c/h update ----
    unsigned hb[8];
#pragma unroll
    for (int m = 0; m < 2; ++m) {
#pragma unroll
      for (int r = 0; r < 4; ++r) {
        float gi = acc[m * 4 + 0][r];
        float gf = acc[m * 4 + 1][r];
        float gg = acc[m * 4 + 2][r];
        float go = acc[m * 4 + 3][r];
        float c = fsigmoid(gf) * cst[m * 4 + r] + fsigmoid(gi) * ftanh_(gg);
        cst[m * 4 + r] = c;
        float h = fsigmoid(go) * ftanh_(c);
        hb[m * 4 + r] = (unsigned)(unsigned short)bf16_of(h);
        if (s == NSTEP - 1) {
          const int rowg = gb * 64 + bh * 32 + m * 16 + l4 * 4 + r;
          hfinal[(size_t)rowg * 512 + colh] = h;
        }
      }
    }

    if (s < NSTEP - 1) {
      // ---- publish h: pair-pack, LDS transpose, 64 coalesced 16B stores ----
      unsigned pk[4];
#pragma unroll
      for (int r = 0; r < 4; ++r) {
        unsigned v0 = hb[r];                       // m=0
        unsigned v1 = hb[4 + r];                   // m=1
        unsigned p0 = (unsigned)__shfl_xor((int)v0, 1);
        unsigned p1 = (unsigned)__shfl_xor((int)v1, 1);
        pk[r] = evenl ? (v0 | (p0 << 16)) : (p1 | (v1 << 16));
      }
#pragma unroll
      for (int r = 0; r < 4; ++r)
        *(unsigned*)(trp + (rbase + r) * 64 + pidx * 4) = pk[r];
      asm volatile("s_waitcnt lgkmcnt(0)" ::: "memory");
      __builtin_amdgcn_s_barrier();

      ux4 pv = *(const ux4*)(trp + prow * 64 + pc * 16);
      char* sb = hnextb + (size_t)(gb * 64 + prow) * 1024 + gn * 64 + pc * 16;
      asm volatile("global_store_dwordx4 %0, %1, off sc0 sc1"
                   :: "v"(sb), "v"(pv) : "memory");
      asm volatile("s_waitcnt vmcnt(0)" ::: "memory");   // acked at coherence point
      __builtin_amdgcn_s_barrier();                      // all waves drained
      if (tid == 0) {
        unsigned sv = (unsigned)(s + 1);
        asm volatile("global_store_dword %0, %1, off sc0 sc1"
                     :: "v"(myfl), "v"(sv) : "memory");
      }
    }
  }
}

// ---------------- heads: exact fp32 VALU GEMM [1024 x 324 x 512] + epilogue --
__global__ __launch_bounds__(256) void heads_kernel(
    const float* __restrict__ hf,
    const float* __restrict__ lin_w, const float* __restrict__ lin_b,
    const float* __restrict__ lv_w,  const float* __restrict__ lv_b,
    const float* __restrict__ u_w,   const float* __restrict__ u_b,
    const float* __restrict__ ww_w,  const float* __restrict__ ww_b,
    const float* __restrict__ bf_w,  const float* __restrict__ bf_b,
    float* __restrict__ out)
{
  __shared__ float hs[64 * 513];
  const int tid = threadIdx.x;
  const int gb = blockIdx.x;     // 0..15
  const int cg = blockIdx.y;     // 0..5, 54 cols each
  for (int i = tid; i < 8192; i += 256) {
    fx4 v = *(const fx4*)(hf + (size_t)gb * 32768 + (size_t)i * 4);
    const int row = i >> 7;
    const int k = (i * 4) & 511;
    float* d = hs + row * 513 + k;
    d[0] = v[0]; d[1] = v[1]; d[2] = v[2]; d[3] = v[3];
  }
  __syncthreads();
  const int r = tid & 63;
  const int cq = tid >> 6;
  const float* hrow = hs + r * 513;
  const int b_ = gb * 64 + r;
#pragma unroll 1
  for (int j = 0; j < 14; ++j) {
    const int cl = cq + 4 * j;
    if (cl >= 54) break;
    const int C = cg * 54 + cl;      // 0..323
    const float* wp; float bv;
    if (C < 32)       { wp = lin_w + (size_t)C * 512;        bv = lin_b[C]; }
    else if (C < 64)  { wp = lv_w + (size_t)(C - 32) * 512;  bv = lv_b[C - 32]; }
    else if (C < 192) { wp = u_w + (size_t)(C - 64) * 512;   bv = u_b[C - 64]; }
    else if (C < 320) { wp = ww_w + (size_t)(C - 192) * 512; bv = ww_b[C - 192]; }
    else              { wp = bf_w + (size_t)(C - 320) * 512; bv = bf_b[C - 320]; }
    float dot = 0.f;
#pragma unroll 8
    for (int k = 0; k < 512; k += 4) {
      fx4 w = *(const fx4*)(wp + k);
      dot += hrow[k] * w[0] + hrow[k + 1] * w[1] + hrow[k + 2] * w[2] + hrow[k + 3] * w[3];
    }
    const float res = bv + dot;
    if (C < 32)       out[(size_t)b_ * 32 + C] = __builtin_amdgcn_exp2f(res * 1.44269504f) * 0.1f;
    else if (C < 64)  out[32768 + (size_t)b_ * 32 + (C - 32)] = res - 5.f;
    else if (C < 192) out[65536 + (size_t)b_ * 128 + (C - 64)] = res;
    else if (C < 320) out[196608 + (size_t)b_ * 128 + (C - 192)] = res;
    else              out[327680 + (size_t)b_ * 4 + (C - 320)] = res;
  }
}

extern "C" void kernel_launch(void* const* d_in, const int* in_sizes, int n_in,
                              void* d_out, int out_size, void* d_ws, size_t ws_size,
                              hipStream_t stream) {
  (void)in_sizes; (void)n_in; (void)out_size; (void)ws_size;
  const float* x     = (const float*)d_in[0];
  const float* a     = (const float*)d_in[1];
  const float* mask  = (const float*)d_in[2];
  const float* w_ih  = (const float*)d_in[3];
  const float* w_hh  = (const float*)d_in[4];
  const float* b_ih  = (const float*)d_in[5];
  const float* b_hh  = (const float*)d_in[6];
  const float* lin_w = (const float*)d_in[7];
  const float* lin_b = (const float*)d_in[8];
  const float* lv_w  = (const float*)d_in[9];
  const float* lv_b  = (const float*)d_in[10];
  const float* u_w   = (const float*)d_in[11];
  const float* u_b   = (const float*)d_in[12];
  const float* ww_w  = (const float*)d_in[13];
  const float* ww_b  = (const float*)d_in[14];
  const float* bf_w  = (const float*)d_in[15];
  const float* bf_b  = (const float*)d_in[16];

  char* ws = (char*)d_ws;
  short* yw       = (short*)(ws);                 // 33,554,432 B: [256][1024][64] bf16
  short* hbuf     = (short*)(ws + 33554432);      //  2,097,152 B: [2][1024][512] bf16
  float* hfinal   = (float*)(ws + 35651584);      //  2,097,152 B
  unsigned* ctr   = (unsigned*)(ws + 37748736);   //     24,576 B (flags region)

  hipMemsetAsync(hbuf, 0, 1024 * 512 * 2, stream);   // h(0) = 0
  hipMemsetAsync(ctr, 0, 24576, stream);

  pack_y_kernel<<<1024, 256, 0, stream>>>(x, a, mask, yw);
  lstm_rec<<<256, 256, 0, stream>>>(yw, w_hh, w_ih, b_ih, b_hh, hbuf, hfinal, ctr);
  heads_kernel<<<dim3(16, 6), 256, 0, stream>>>(hfinal, lin_w, lin_b, lv_w, lv_b,
                                                u_w, u_b, ww_w, ww_b, bf_w, bf_b,
                                                (float*)d_out);
}